// Round 1
// baseline (196.584 us; speedup 1.0000x reference)
//
#include <hip/hip_runtime.h>
#include <math.h>

#define NB 4096
#define NC 3
#define ND 512
#define NBC (NB + NC)                 // 4099
#define ADJ ((size_t)NBC * (size_t)NBC)
#define NCHUNK 32
#define ROWS_PER_CHUNK (NB / NCHUNK)  // 128

static constexpr float HALF_INV_DELTA = 0.5f / 1.5f;

// ws layout (float offsets)
#define OFF_CNT   0                            // int counts[9]
#define OFF_PART  16                           // [3][NCHUNK][3][ND] = 147456
#define OFF_CENT  (OFF_PART + 3*NCHUNK*3*ND)   // 147472 : centers [3][3][ND]
#define OFF_C2    (OFF_CENT + 9*ND)            // 152080 : ||center||^2 [9]
#define OFF_AVG   (OFF_C2 + 16)                // 152096 : avg_centers [3][ND]
#define OFF_STATS (OFF_AVG + 3*ND)             // 153632 : stats [NB][3][12]
// per-sample per-modality 12 floats: p0 p1 p2 | lps0 lps1 lps2 | F0 F1 F2 | Bs | a=1-Bs | pred

__device__ __forceinline__ float dot8(const float4& a, const float4& b,
                                      const float4& c, const float4& d) {
    return a.x*c.x + a.y*c.y + a.z*c.z + a.w*c.w +
           b.x*d.x + b.y*d.y + b.z*d.z + b.w*d.w;
}

__device__ __forceinline__ float wred(float v) {
    #pragma unroll
    for (int off = 32; off > 0; off >>= 1) v += __shfl_xor(v, off, 64);
    return v;
}

// ---- kernel A: per-sample label stats + class counts -----------------------
__global__ void __launch_bounds__(256) kA(const float* __restrict__ tl,
                                          const float* __restrict__ al,
                                          const float* __restrict__ vl,
                                          float* __restrict__ ws) {
    int i = blockIdx.x * 256 + threadIdx.x;
    __shared__ int cnt[9];
    if (threadIdx.x < 9) cnt[threadIdx.x] = 0;
    __syncthreads();
    const float* labs[3] = {tl, al, vl};
    float* st = ws + OFF_STATS + (size_t)i * 36;
    #pragma unroll
    for (int m = 0; m < 3; ++m) {
        float p0 = labs[m][i*3+0], p1 = labs[m][i*3+1], p2 = labs[m][i*3+2];
        float l0 = logf(p0), l1 = logf(p1), l2 = logf(p2);
        float self = p0*l0 + p1*l1 + p2*l2;
        int pred = 0; float pm = p0;
        if (p1 > pm) { pred = 1; pm = p1; }
        if (p2 > pm) { pred = 2; }
        float Bs = HALF_INV_DELTA * self;
        float* s = st + m*12;
        s[0] = p0; s[1] = p1; s[2] = p2;
        s[3] = HALF_INV_DELTA*l0; s[4] = HALF_INV_DELTA*l1; s[5] = HALF_INV_DELTA*l2;
        // slots 6..8 (F) filled by kD
        s[9]  = Bs;
        s[10] = 1.0f - Bs;
        s[11] = (float)pred;
        atomicAdd(&cnt[m*3 + pred], 1);
    }
    __syncthreads();
    if (threadIdx.x < 9) atomicAdd((int*)ws + OFF_CNT + threadIdx.x, cnt[threadIdx.x]);
}

// ---- kernel B: per-chunk class sums (register accumulators, no atomics) ----
__global__ void __launch_bounds__(256) kB(const float* __restrict__ tf,
                                          const float* __restrict__ af,
                                          const float* __restrict__ vf,
                                          float* __restrict__ ws) {
    int chunk = blockIdx.x, m = blockIdx.y, t = threadIdx.x;
    const float* feats[3] = {tf, af, vf};
    const float* z = feats[m];
    float acc[3][2] = {};
    int r0 = chunk * ROWS_PER_CHUNK;
    const float* st = ws + OFF_STATS;
    for (int r = 0; r < ROWS_PER_CHUNK; ++r) {
        int i = r0 + r;
        int pred = (int)st[(size_t)i*36 + m*12 + 11];
        float z0 = z[(size_t)i*ND + t];
        float z1 = z[(size_t)i*ND + t + 256];
        #pragma unroll
        for (int c = 0; c < 3; ++c) {
            acc[c][0] += (pred == c) ? z0 : 0.0f;
            acc[c][1] += (pred == c) ? z1 : 0.0f;
        }
    }
    float* part = ws + OFF_PART + ((size_t)m*NCHUNK + chunk) * 3 * ND;
    #pragma unroll
    for (int c = 0; c < 3; ++c) {
        part[c*ND + t]       = acc[c][0];
        part[c*ND + t + 256] = acc[c][1];
    }
}

// ---- kernel C: finalize centers + ||center||^2 -----------------------------
__global__ void __launch_bounds__(256) kC(float* __restrict__ ws) {
    int mc = blockIdx.x;            // m*3+c
    int m = mc / 3, c = mc % 3, t = threadIdx.x;
    float s0 = 0.0f, s1 = 0.0f;
    for (int ch = 0; ch < NCHUNK; ++ch) {
        const float* part = ws + OFF_PART + (((size_t)m*NCHUNK + ch)*3 + c) * ND;
        s0 += part[t];
        s1 += part[t + 256];
    }
    int cnt = ((const int*)ws)[OFF_CNT + mc];
    float inv = 1.0f / fmaxf((float)cnt, 1.0f);
    float c0 = s0 * inv, c1 = s1 * inv;
    float* cent = ws + OFF_CENT + (size_t)mc * ND;
    cent[t] = c0; cent[t + 256] = c1;
    __shared__ float red[256];
    red[t] = c0*c0 + c1*c1;
    __syncthreads();
    for (int s = 128; s > 0; s >>= 1) {
        if (t < s) red[t] += red[t + s];
        __syncthreads();
    }
    if (t == 0) ws[OFF_C2 + mc] = red[0];
}

// ---- kernel C2: avg centers + node_features tail + eye(3) ------------------
__global__ void __launch_bounds__(512) kC2(float* __restrict__ ws, float* __restrict__ out) {
    int c = blockIdx.x, d = threadIdx.x;
    float a = (ws[OFF_CENT + (0*3 + c)*ND + d] +
               ws[OFF_CENT + (1*3 + c)*ND + d] +
               ws[OFF_CENT + (2*3 + c)*ND + d]) * (1.0f/3.0f);
    ws[OFF_AVG + c*ND + d] = a;
    out[ADJ + (size_t)(NB + c)*ND + d] = a;
    if (c == 0 && d < 9) {
        int r = d / 3, cc = d % 3;
        out[(size_t)(NB + r)*NBC + NB + cc] = (r == cc) ? 1.0f : 0.0f;
    }
}

// ---- kernel D: wave-per-sample heavy stats (F factors, fused border) -------
__global__ void __launch_bounds__(256) kD(const float* __restrict__ tf,
                                          const float* __restrict__ af,
                                          const float* __restrict__ vf,
                                          const float* __restrict__ fused,
                                          const float* __restrict__ ccp,
                                          float* __restrict__ ws,
                                          float* __restrict__ out) {
    int wid = threadIdx.x >> 6, lane = threadIdx.x & 63;
    int i = blockIdx.x * 4 + wid;
    const float* feats[3] = {tf, af, vf};
    int d0 = lane * 8;
    float* st = ws + OFF_STATS + (size_t)i * 36;

    #pragma unroll
    for (int m = 0; m < 3; ++m) {
        const float4* z4 = (const float4*)(feats[m] + ((size_t)i << 9) + d0);
        float4 za = z4[0], zb = z4[1];
        float v0 = dot8(za, zb, za, zb);
        const float4* c40 = (const float4*)(ws + OFF_CENT + (size_t)(m*3+0)*ND + d0);
        float v1 = dot8(za, zb, c40[0], c40[1]);
        const float4* c41 = (const float4*)(ws + OFF_CENT + (size_t)(m*3+1)*ND + d0);
        float v2 = dot8(za, zb, c41[0], c41[1]);
        const float4* c42 = (const float4*)(ws + OFF_CENT + (size_t)(m*3+2)*ND + d0);
        float v3 = dot8(za, zb, c42[0], c42[1]);
        v0 = wred(v0); v1 = wred(v1); v2 = wred(v2); v3 = wred(v3);
        if (lane == 0) {
            st[m*12 + 6] = expf(v1 - 0.5f*(v0 + ws[OFF_C2 + m*3 + 0]));
            st[m*12 + 7] = expf(v2 - 0.5f*(v0 + ws[OFF_C2 + m*3 + 1]));
            st[m*12 + 8] = expf(v3 - 0.5f*(v0 + ws[OFF_C2 + m*3 + 2]));
        }
    }

    // fused pseudo-label argmax + w_center
    const float4* f4 = (const float4*)(fused + ((size_t)i << 9) + d0);
    float4 fa = f4[0], fb = f4[1];
    const float4* p0 = (const float4*)(ccp + 0*ND + d0);
    const float4* p1 = (const float4*)(ccp + 1*ND + d0);
    const float4* p2 = (const float4*)(ccp + 2*ND + d0);
    float l0 = wred(dot8(fa, fb, p0[0], p0[1]));
    float l1 = wred(dot8(fa, fb, p1[0], p1[1]));
    float l2 = wred(dot8(fa, fb, p2[0], p2[1]));
    int pf = 0; float lm = l0;
    if (l1 > lm) { pf = 1; lm = l1; }
    if (l2 > lm) { pf = 2; }
    const float4* av = (const float4*)(ws + OFF_AVG + (size_t)pf*ND + d0);
    float4 aa = av[0], ab = av[1];
    float dxx = fa.x-aa.x, dxy = fa.y-aa.y, dxz = fa.z-aa.z, dxw = fa.w-aa.w;
    float dyx = fb.x-ab.x, dyy = fb.y-ab.y, dyz = fb.z-ab.z, dyw = fb.w-ab.w;
    float dsq = wred(dxx*dxx + dxy*dxy + dxz*dxz + dxw*dxw +
                     dyx*dyx + dyy*dyy + dyz*dyz + dyw*dyw);
    if (lane == 0) {
        float wc = expf(-0.5f * dsq);
        #pragma unroll
        for (int c = 0; c < 3; ++c) {
            float v = (c == pf) ? wc : 0.0f;
            out[(size_t)i*NBC + NB + c]   = v;   // top-right block
            out[(size_t)(NB + c)*NBC + i] = v;   // bottom-left block
        }
    }
}

// ---- kernel E: the B x B adjacency block -----------------------------------
__global__ void __launch_bounds__(256) kE(const float* __restrict__ ws,
                                          float* __restrict__ out) {
    int j = blockIdx.x * 256 + threadIdx.x;
    int rowBase = blockIdx.y * 64;
    const float* st = ws + OFF_STATS;

    // per-column (j) data in registers
    float jp[3][3], jl[3][3], jF[3][3], jBs[3], jpred[3];
    #pragma unroll
    for (int m = 0; m < 3; ++m) {
        const float* s = st + (size_t)j*36 + m*12;
        jp[m][0] = s[0]; jp[m][1] = s[1]; jp[m][2] = s[2];
        jl[m][0] = s[3]; jl[m][1] = s[4]; jl[m][2] = s[5];
        jF[m][0] = s[6]; jF[m][1] = s[7]; jF[m][2] = s[8];
        jBs[m] = s[9]; jpred[m] = s[11];
    }

    for (int r = 0; r < 64; ++r) {
        int i = rowBase + r;
        const float* si = st + (size_t)i*36;   // uniform address -> scalar loads
        float sum = 0.0f;
        #pragma unroll
        for (int m = 0; m < 3; ++m) {
            const float* sm = si + m*12;
            float t = sm[10] - jBs[m];                       // 1 - Bs_i - Bs_j
            t += sm[0]*jl[m][0] + sm[1]*jl[m][1] + sm[2]*jl[m][2];   // p_i . lps_j
            t += jp[m][0]*sm[3] + jp[m][1]*sm[4] + jp[m][2]*sm[5];   // p_j . lps_i
            t = fmaxf(t, 0.0f);                              // t>0 <=> skl<DELTA
            float pi = sm[11];
            float Fj = (pi == 0.0f) ? jF[m][0] : ((pi == 1.0f) ? jF[m][1] : jF[m][2]);
            float pj = jpred[m];
            float Fi = (pj == 0.0f) ? sm[6] : ((pj == 1.0f) ? sm[7] : sm[8]);
            sum += t * (Fi * Fj);
        }
        float outv = (i == j) ? 0.0f : sum * (1.0f/3.0f);
        out[(size_t)i*NBC + j] = outv;
    }
}

extern "C" void kernel_launch(void* const* d_in, const int* in_sizes, int n_in,
                              void* d_out, int out_size, void* d_ws, size_t ws_size,
                              hipStream_t stream) {
    const float* tf    = (const float*)d_in[0];
    const float* af    = (const float*)d_in[1];
    const float* vf    = (const float*)d_in[2];
    const float* tl    = (const float*)d_in[3];
    const float* al    = (const float*)d_in[4];
    const float* vl    = (const float*)d_in[5];
    const float* fused = (const float*)d_in[6];
    const float* ccp   = (const float*)d_in[7];
    float* out = (float*)d_out;
    float* ws  = (float*)d_ws;

    // zero the atomic count slots
    hipMemsetAsync(ws, 0, 64, stream);

    kA<<<NB/256, 256, 0, stream>>>(tl, al, vl, ws);
    kB<<<dim3(NCHUNK, 3), 256, 0, stream>>>(tf, af, vf, ws);
    kC<<<9, 256, 0, stream>>>(ws);
    kC2<<<3, 512, 0, stream>>>(ws, out);
    kD<<<NB/4, 256, 0, stream>>>(tf, af, vf, fused, ccp, ws, out);
    kE<<<dim3(NB/256, NB/64), 256, 0, stream>>>(ws, out);

    // node_features rows 0..NB-1 = fused_representations (contiguous copy)
    hipMemcpyAsync(out + ADJ, fused, (size_t)NB * ND * sizeof(float),
                   hipMemcpyDeviceToDevice, stream);
}